// Round 2
// baseline (177.440 us; speedup 1.0000x reference)
//
#include <hip/hip_runtime.h>
#include <hip/hip_bf16.h>
#include <math.h>

#define Bg   128
#define Nn   64
#define Tt   256
#define INF  320      // Nn + Tt
#define Hd   256
#define OUTD 128
#define Ee   2016     // Nn*(Nn-1)/2
#define TOTE (Bg*Ee)  // 258048
#define SCOLS 576     // padded 514 -> 9*64 so GEMM2 tiles exactly
#define MROWS 8192    // Bg*Nn

#define RSQRT_LN2 1.2011224087864498f   // 1/sqrt(ln2): mean cols pre-scale
#define LOG2E     1.4426950408889634f
#define EPS_T     1.45719e-6f           // 1.01e-6 * log2e

typedef __attribute__((ext_vector_type(8))) short bf16x8;
typedef __attribute__((ext_vector_type(4))) float f32x4;

static __device__ __forceinline__ ushort f2bf(float v) {
    __hip_bfloat16 h = __float2bfloat16(v);
    return *(ushort*)&h;
}

// ---------------- prep: WgT->bf16, packed WcatT->bf16, ebias, red init ----------------
#define CVT_N (INF * Hd)                  // 81920
#define PACK_N (Hd * SCOLS)               // 147456
__global__ void k_prep(const float* __restrict__ Wg, const float* __restrict__ Wm,
                       const float* __restrict__ Wv, const float* __restrict__ Ww,
                       const float* __restrict__ bm, const float* __restrict__ bv,
                       const float* __restrict__ bw,
                       ushort* __restrict__ WgbT, ushort* __restrict__ WcatT,
                       float* __restrict__ ebias, unsigned* __restrict__ red) {
    int idx = blockIdx.x * 256 + threadIdx.x;
    if (idx == 0) { red[0] = 0u; red[1] = 0u; }
    if (idx < CVT_N) {
        int n = idx / INF, k = idx - n * INF;
        WgbT[idx] = f2bf(Wg[k * Hd + n]);
        return;
    }
    idx -= CVT_N;
    if (idx < PACK_N) {
        int n = idx / Hd, k = idx - n * Hd;   // n = output col, k = reduction
        float v = 0.f;
        if (n < 128)       v = Wm[k * 128 + n];
        else if (n < 256)  v = Wm[(256 + k) * 128 + (n - 128)];
        else if (n < 384)  v = Wv[k * 128 + (n - 256)];
        else if (n < 512)  v = Wv[(256 + k) * 128 + (n - 384)];
        else if (n == 512) v = Ww[k];
        else if (n == 513) v = Ww[256 + k];
        WcatT[idx] = f2bf(v);
        return;
    }
    idx -= PACK_N;
    if (idx >= SCOLS) return;
    float e = 0.f;
    if (idx < 128)                    e = bm[idx];
    else if (idx >= 256 && idx < 384) e = bv[idx - 256];
    else if (idx == 512)              e = bw[0];
    ebias[idx] = e;
}

// ---------------- prefix-mean aggregation: LDS-tiled coalesced scan ----------------
__global__ __launch_bounds__(256) void k_agg(const float* __restrict__ topo,
                                             const float* __restrict__ temp,
                                             ushort* __restrict__ agg) {
    __shared__ float T[64 * 65];
    const int b = blockIdx.x, ft = blockIdx.y;
    const int tid = threadIdx.x;
    const int row = tid >> 2, seg = tid & 3;
    const float* src = (ft == 0) ? (topo + (size_t)(b * Nn + row) * Nn)
                                 : (temp + (size_t)(b * Nn + row) * Tt + (ft - 1) * 64);
    #pragma unroll
    for (int i = 0; i < 4; ++i) {
        float4 v = *(const float4*)(src + seg * 16 + i * 4);
        float* d = &T[row * 65 + seg * 16 + i * 4];
        d[0] = v.x; d[1] = v.y; d[2] = v.z; d[3] = v.w;
    }
    __syncthreads();
    const int w = tid >> 6, lane = tid & 63;
    #pragma unroll
    for (int k = 0; k < 16; ++k) {
        int f = w * 16 + k;
        float x = T[lane * 65 + f];
        float incl = x;
        #pragma unroll
        for (int o = 1; o < 64; o <<= 1) {
            float t = __shfl_up(incl, o);
            if (lane >= o) incl += t;
        }
        float excl = incl - x;
        T[lane * 65 + f] = lane ? excl * __builtin_amdgcn_rcpf((float)lane) : 0.f;
    }
    __syncthreads();
    const int node = tid >> 2, f0 = (tid & 3) * 16;
    ushort tmp[16];
    #pragma unroll
    for (int i = 0; i < 16; ++i) tmp[i] = f2bf(T[node * 65 + f0 + i]);
    ushort* dst = agg + (size_t)(b * Nn + node) * INF + ft * 64 + f0;
    *(uint4*)dst = *(uint4*)tmp;
    *(uint4*)(dst + 8) = *(uint4*)(tmp + 8);
}

// ---------------- bf16 MFMA GEMM, 64x64 tile, BK=64, B pre-transposed ----------------
// edgeScale (transC only): cols 0-255 *= 1/sqrt(ln2); cols 256-511 -> exp(v)
// (stored as e^v so the edge kernel's softplus is log2(1+e_i*e_j): 1 transc).
__global__ __launch_bounds__(256) void k_gemm_mfma(const ushort* __restrict__ A,
                                                   const ushort* __restrict__ BT,
                                                   const float* __restrict__ bias,
                                                   ushort* __restrict__ Cb,
                                                   float* __restrict__ Cf,
                                                   int N, int K, int relu, int transC,
                                                   int edgeScale) {
    __shared__ ushort Asl[64 * 72];
    __shared__ ushort Bsl[64 * 72];   // [n][k]
    const int tid = threadIdx.x;
    const int w = tid >> 6, lane = tid & 63;
    const int quad = lane >> 4, r16 = lane & 15;
    const int m0 = blockIdx.y * 64, n0 = blockIdx.x * 64;
    const int row = tid >> 2, seg = tid & 3;
    f32x4 acc[4] = {};

    for (int k0 = 0; k0 < K; k0 += 64) {
        const ushort* ap = A + (size_t)(m0 + row) * K + k0 + seg * 16;
        uint4 a0 = ((const uint4*)ap)[0];
        uint4 a1 = ((const uint4*)ap)[1];
        *(uint4*)(Asl + row * 72 + seg * 16)     = a0;
        *(uint4*)(Asl + row * 72 + seg * 16 + 8) = a1;
        const ushort* bp = BT + (size_t)(n0 + row) * K + k0 + seg * 16;
        uint4 b0 = ((const uint4*)bp)[0];
        uint4 b1 = ((const uint4*)bp)[1];
        *(uint4*)(Bsl + row * 72 + seg * 16)     = b0;
        *(uint4*)(Bsl + row * 72 + seg * 16 + 8) = b1;
        __syncthreads();

        bf16x8 af0 = *(const bf16x8*)(Asl + (w * 16 + r16) * 72 + quad * 8);
        bf16x8 af1 = *(const bf16x8*)(Asl + (w * 16 + r16) * 72 + 32 + quad * 8);
        #pragma unroll
        for (int ns = 0; ns < 4; ++ns) {
            bf16x8 bf0 = *(const bf16x8*)(Bsl + (ns * 16 + r16) * 72 + quad * 8);
            bf16x8 bf1 = *(const bf16x8*)(Bsl + (ns * 16 + r16) * 72 + 32 + quad * 8);
            acc[ns] = __builtin_amdgcn_mfma_f32_16x16x32_bf16(af0, bf0, acc[ns], 0, 0, 0);
            acc[ns] = __builtin_amdgcn_mfma_f32_16x16x32_bf16(af1, bf1, acc[ns], 0, 0, 0);
        }
        __syncthreads();
    }

    const int row0 = m0 + w * 16 + quad * 4;
    #pragma unroll
    for (int ns = 0; ns < 4; ++ns) {
        f32x4 a = acc[ns];
        int col = n0 + ns * 16 + r16;
        float bb = bias ? bias[col] : 0.f;
        float vv[4];
        #pragma unroll
        for (int i = 0; i < 4; ++i) {
            float v = a[i] + bb;
            if (relu) v = fmaxf(v, 0.f);
            vv[i] = v;
        }
        if (transC) {
            if (edgeScale) {
                if (col < 256) {
                    #pragma unroll
                    for (int i = 0; i < 4; ++i) vv[i] *= RSQRT_LN2;
                } else if (col < 512) {
                    #pragma unroll
                    for (int i = 0; i < 4; ++i)
                        vv[i] = __builtin_amdgcn_exp2f(vv[i] * LOG2E);  // e^v
                }
            }
            *(float4*)(Cf + (size_t)col * MROWS + row0) = make_float4(vv[0], vv[1], vv[2], vv[3]);
        } else {
            #pragma unroll
            for (int i = 0; i < 4; ++i) {
                int row2 = row0 + i;
                if (Cb) Cb[(size_t)row2 * N + col] = f2bf(vv[i]);
                else    Cf[(size_t)row2 * N + col] = vv[i];
            }
        }
    }
}

// ---------------- edge kernel: whole-graph tile, 2x2 pair blocking, o-split x4 ----------------
// 512 blocks = 128 graphs x 4 o-chunks of 32. Block = 512 threads.
// LDS: L[0]=mean-src rows 0-127, L[1]=mean-dst 128-255, L[2]=e^v-src 256-383,
// L[3]=e^v-dst 384-511; each [64 nodes][36] f32, XOR-swizzled col c^(((n>>1)&7)<<2)
// so 2x2-blocked (even-row) ds_read_b128 spreads across all 8 bank-quads.
// Threads 0-495: strict 2x2 cell (ci<cj) -> 4 edges, shares 8 b128 reads over 16 eterms.
// Threads 496-511: two diagonal cells -> edges (2d,2d+1); same read shape, 2 eterm sets.
// eterm (pre-scaled inputs): m'^2 * rcp(log2(1+Ei*Ej) + eps') == m^2/(softplus(v)+1.01e-6).
static __device__ __forceinline__ float et(float mA, float mB, float eA, float eB) {
    float m = mA + mB;                       // mean, pre-scaled by 1/sqrt(ln2)
    float E = eA * eB;                       // e^{vi+vj}
    float t = __builtin_amdgcn_logf(1.f + E) + EPS_T;   // softplus * log2e
    return m * m * __builtin_amdgcn_rcpf(t);
}

__global__ __launch_bounds__(512, 4) void k_edge5(const float* __restrict__ ST,
                                                  float* __restrict__ accp) {
    __shared__ float L[4][64][36];
    const int bid = blockIdx.x;
    const int b = bid >> 2, oc = bid & 3;
    const int tid = threadIdx.x;

    // stage: 4 arrays x 32 o-rows x 64 nodes (16 quads); 4 float4 per thread
    {
        const int c = (tid >> 4) & 31, q = tid & 15, n = q << 2;
        const int s0 = c ^ ((((n    ) >> 1) & 7) << 2);
        const int s1 = c ^ ((((n + 1) >> 1) & 7) << 2);
        const int s2 = c ^ ((((n + 2) >> 1) & 7) << 2);
        const int s3 = c ^ ((((n + 3) >> 1) & 7) << 2);
        #pragma unroll
        for (int arr = 0; arr < 4; ++arr) {
            float4 v = *(const float4*)&ST[(size_t)(arr * 128 + oc * 32 + c) * MROWS
                                           + b * 64 + n];
            L[arr][n + 0][s0] = v.x;
            L[arr][n + 1][s1] = v.y;
            L[arr][n + 2][s2] = v.z;
            L[arr][n + 3][s3] = v.w;
        }
    }

    // pair decode
    const bool strict = tid < 496;
    int ri0, ri1, rj0, rj1;
    if (strict) {
        int rr = tid, ci = 0;
        while (rr >= 31 - ci) { rr -= 31 - ci; ++ci; }
        int cj = ci + 1 + rr;
        ri0 = 2 * ci; ri1 = ri0 + 1;
        rj0 = 2 * cj; rj1 = rj0 + 1;
    } else {
        int d0 = (tid - 496) * 2, d1 = d0 + 1;
        ri0 = 2 * d0; rj0 = ri0 + 1;   // edge (ri0, ri0+1)
        ri1 = 2 * d1; rj1 = ri1 + 1;   // edge (ri1, ri1+1)
    }
    const float* M0 = &L[0][ri0][0]; const float* M1 = &L[0][ri1][0];
    const float* N0 = &L[1][rj0][0]; const float* N1 = &L[1][rj1][0];
    const float* E0 = &L[2][ri0][0]; const float* E1 = &L[2][ri1][0];
    const float* F0 = &L[3][rj0][0]; const float* F1 = &L[3][rj1][0];
    const int si0 = ((ri0 >> 1) & 7) << 2, si1 = ((ri1 >> 1) & 7) << 2;
    const int sj0 = ((rj0 >> 1) & 7) << 2, sj1 = ((rj1 >> 1) & 7) << 2;

    __syncthreads();

    float a00 = 0.f, a01 = 0.f, a10 = 0.f, a11 = 0.f;
    #pragma unroll 4
    for (int t = 0; t < 32; t += 4) {
        float4 m0 = *(const float4*)(M0 + (t ^ si0));
        float4 m1 = *(const float4*)(M1 + (t ^ si1));
        float4 n0 = *(const float4*)(N0 + (t ^ sj0));
        float4 n1 = *(const float4*)(N1 + (t ^ sj1));
        float4 e0 = *(const float4*)(E0 + (t ^ si0));
        float4 e1 = *(const float4*)(E1 + (t ^ si1));
        float4 f0 = *(const float4*)(F0 + (t ^ sj0));
        float4 f1 = *(const float4*)(F1 + (t ^ sj1));
        a00 += et(m0.x,n0.x,e0.x,f0.x) + et(m0.y,n0.y,e0.y,f0.y)
             + et(m0.z,n0.z,e0.z,f0.z) + et(m0.w,n0.w,e0.w,f0.w);
        a11 += et(m1.x,n1.x,e1.x,f1.x) + et(m1.y,n1.y,e1.y,f1.y)
             + et(m1.z,n1.z,e1.z,f1.z) + et(m1.w,n1.w,e1.w,f1.w);
        if (strict) {
            a01 += et(m0.x,n1.x,e0.x,f1.x) + et(m0.y,n1.y,e0.y,f1.y)
                 + et(m0.z,n1.z,e0.z,f1.z) + et(m0.w,n1.w,e0.w,f1.w);
            a10 += et(m1.x,n0.x,e1.x,f0.x) + et(m1.y,n0.y,e1.y,f0.y)
                 + et(m1.z,n0.z,e1.z,f0.z) + et(m1.w,n0.w,e1.w,f0.w);
        }
    }

    float* ap = accp + (size_t)oc * TOTE + (size_t)b * Ee;
    if (strict) {
        int e0i = (ri0 * (127 - ri0)) / 2 + (rj0 - ri0 - 1);
        int e1i = (ri1 * (127 - ri1)) / 2 + (rj0 - ri1 - 1);
        ap[e0i] = a00; ap[e0i + 1] = a01;
        ap[e1i] = a10; ap[e1i + 1] = a11;
    } else {
        ap[(ri0 * (127 - ri0)) / 2] = a00;
        ap[(ri1 * (127 - ri1)) / 2] = a11;
    }
}

// ---------------- gumbel/sigmoid numerator + softmax denominator ----------------
__global__ __launch_bounds__(256) void k_den(const float* __restrict__ ST,
                                             const float* __restrict__ gu,
                                             float* __restrict__ numer,
                                             unsigned* __restrict__ red) {
    __shared__ float sred[4];
    const int tid = threadIdx.x;
    int idx = blockIdx.x * 256 + tid;
    int b = idx >> 12, rem = idx & 4095;
    int r = rem >> 6, c = rem & 63;
    float en = 0.f;
    if (c > r) {
        int e = b * Ee + (r * (127 - r)) / 2 + (c - r - 1);
        float wr = ST[(size_t)512 * MROWS + b * 64 + r]
                 + ST[(size_t)513 * MROWS + b * 64 + c];
        float w  = __builtin_amdgcn_rcpf(1.f + __expf(-wr));
        float g  = -__logf(-__logf(gu[e]));
        en = __expf((w + g) * 2.0f);           // exp(logit/T), logit <= ~36: safe
        numer[e] = en;
    }
    float s = en;
    #pragma unroll
    for (int o = 32; o; o >>= 1) s += __shfl_down(s, o);
    if ((tid & 63) == 0) sred[tid >> 6] = s;
    __syncthreads();
    if (tid == 0) atomicAdd((float*)&red[1], sred[0] + sred[1] + sred[2] + sred[3]);
}

// ---------------- final scatter: combine acc partials, normalize, zero-fill ----------------
__global__ void k_out(const float* __restrict__ accp, const float* __restrict__ numer,
                      const unsigned* __restrict__ red, float* __restrict__ out) {
    int idx = blockIdx.x * 256 + threadIdx.x;
    if (idx >= Bg * Nn * Nn) return;
    int b = idx >> 12;
    int rem = idx & 4095;
    int r = rem >> 6, c = rem & 63;
    float v = 0.f;
    if (c > r) {
        int e = b * Ee + (r * (127 - r)) / 2 + (c - r - 1);
        float a = accp[e] + accp[TOTE + e] + accp[2 * TOTE + e] + accp[3 * TOTE + e];
        float se = __expf(a * (-1.f / 256.f));
        float Sinv = __builtin_amdgcn_rcpf(((const float*)red)[1]);
        v = se * numer[e] * Sinv;
    }
    out[idx] = v;
}

extern "C" void kernel_launch(void* const* d_in, const int* in_sizes, int n_in,
                              void* d_out, int out_size, void* d_ws, size_t ws_size,
                              hipStream_t stream) {
    const float* topo = (const float*)d_in[0];
    const float* temp = (const float*)d_in[1];
    const float* gu   = (const float*)d_in[2];
    const float* Wg   = (const float*)d_in[3];
    const float* bg   = (const float*)d_in[4];
    const float* Wm   = (const float*)d_in[5];
    const float* bm   = (const float*)d_in[6];
    const float* Wv   = (const float*)d_in[7];
    const float* bv   = (const float*)d_in[8];
    const float* Ww   = (const float*)d_in[9];
    const float* bw   = (const float*)d_in[10];
    float* out = (float*)d_out;

    char* ws = (char*)d_ws;
    size_t off = 0;
    auto carve = [&](size_t bytes) { char* p = ws + off; off = (off + bytes + 255) & ~(size_t)255; return p; };

    // r1 hosts aggb (bf16, 5.2 MB) pre-GEMM1, then S_T[576][8192] f32 (18.9 MB).
    char*   r1    = carve((size_t)SCOLS * MROWS * 4);
    float*  ST    = (float*)r1;
    ushort* aggb  = (ushort*)r1;
    ushort* hb    = (ushort*)carve((size_t)MROWS * Hd * 2);      // 4.19 MB
    ushort* WgbT  = (ushort*)carve((size_t)INF * Hd * 2);        // 0.16 MB
    ushort* WcatT = (ushort*)carve((size_t)Hd * SCOLS * 2);      // 0.29 MB
    float*  ebias = (float*)carve((size_t)SCOLS * 4);
    float*  numer = (float*)carve((size_t)TOTE * 4);             // 1.03 MB
    float*  accp  = (float*)carve((size_t)4 * TOTE * 4);         // 4.13 MB
    unsigned* red = (unsigned*)carve(256);

    k_prep<<<(CVT_N + PACK_N + SCOLS + 255) / 256, 256, 0, stream>>>(
        Wg, Wm, Wv, Ww, bm, bv, bw, WgbT, WcatT, ebias, red);
    k_agg<<<dim3(Bg, INF / 64), 256, 0, stream>>>(topo, temp, aggb);
    // GEMM1: hb[8192,256] = relu(aggb[8192,320] @ WgbT^T + bg)
    k_gemm_mfma<<<dim3(Hd / 64, MROWS / 64), 256, 0, stream>>>(
        aggb, WgbT, bg, hb, nullptr, Hd, INF, 1, 0, 0);
    // GEMM2: ST[576][8192] = colxf((hb[8192,256] @ WcatT^T + ebias))^T
    k_gemm_mfma<<<dim3(SCOLS / 64, MROWS / 64), 256, 0, stream>>>(
        hb, WcatT, ebias, nullptr, ST, SCOLS, Hd, 0, 1, 1);
    k_edge5<<<Bg * 4, 512, 0, stream>>>(ST, accp);
    k_den<<<(Bg * Nn * Nn) / 256, 256, 0, stream>>>(ST, gu, numer, red);
    k_out<<<(Bg * Nn * Nn + 255) / 256, 256, 0, stream>>>(accp, numer, red, out);
}

// Round 3
// 157.399 us; speedup vs baseline: 1.1273x; 1.1273x over previous
//
#include <hip/hip_runtime.h>
#include <hip/hip_bf16.h>
#include <math.h>

#define Bg   128
#define Nn   64
#define Tt   256
#define INF  320      // Nn + Tt
#define Hd   256
#define OUTD 128
#define Ee   2016     // Nn*(Nn-1)/2
#define TOTE (Bg*Ee)  // 258048
#define SCOLS 576     // padded 514 -> 9*64 so GEMM2 tiles exactly
#define MROWS 8192    // Bg*Nn

#define RSQRT_LN2 1.2011224087864498f   // 1/sqrt(ln2): mean cols pre-scale
#define LOG2E     1.4426950408889634f
#define EPS_T     1.45719e-6f           // 1.01e-6 * log2e

typedef __attribute__((ext_vector_type(8))) short bf16x8;
typedef __attribute__((ext_vector_type(4))) float f32x4;

static __device__ __forceinline__ ushort f2bf(float v) {
    __hip_bfloat16 h = __float2bfloat16(v);
    return *(ushort*)&h;
}

// ---------------- prep: WgT->bf16, packed WcatT->bf16, ebias, red init ----------------
#define CVT_N (INF * Hd)                  // 81920
#define PACK_N (Hd * SCOLS)               // 147456
__global__ void k_prep(const float* __restrict__ Wg, const float* __restrict__ Wm,
                       const float* __restrict__ Wv, const float* __restrict__ Ww,
                       const float* __restrict__ bm, const float* __restrict__ bv,
                       const float* __restrict__ bw,
                       ushort* __restrict__ WgbT, ushort* __restrict__ WcatT,
                       float* __restrict__ ebias, unsigned* __restrict__ red) {
    int idx = blockIdx.x * 256 + threadIdx.x;
    if (idx == 0) { red[0] = 0u; red[1] = 0u; }
    if (idx < CVT_N) {
        int n = idx / INF, k = idx - n * INF;
        WgbT[idx] = f2bf(Wg[k * Hd + n]);
        return;
    }
    idx -= CVT_N;
    if (idx < PACK_N) {
        int n = idx / Hd, k = idx - n * Hd;   // n = output col, k = reduction
        float v = 0.f;
        if (n < 128)       v = Wm[k * 128 + n];
        else if (n < 256)  v = Wm[(256 + k) * 128 + (n - 128)];
        else if (n < 384)  v = Wv[k * 128 + (n - 256)];
        else if (n < 512)  v = Wv[(256 + k) * 128 + (n - 384)];
        else if (n == 512) v = Ww[k];
        else if (n == 513) v = Ww[256 + k];
        WcatT[idx] = f2bf(v);
        return;
    }
    idx -= PACK_N;
    if (idx >= SCOLS) return;
    float e = 0.f;
    if (idx < 128)                    e = bm[idx];
    else if (idx >= 256 && idx < 384) e = bv[idx - 256];
    else if (idx == 512)              e = bw[0];
    ebias[idx] = e;
}

// ---------------- prefix-mean aggregation: LDS-tiled coalesced scan ----------------
__global__ __launch_bounds__(256) void k_agg(const float* __restrict__ topo,
                                             const float* __restrict__ temp,
                                             ushort* __restrict__ agg) {
    __shared__ float T[64 * 65];
    const int b = blockIdx.x, ft = blockIdx.y;
    const int tid = threadIdx.x;
    const int row = tid >> 2, seg = tid & 3;
    const float* src = (ft == 0) ? (topo + (size_t)(b * Nn + row) * Nn)
                                 : (temp + (size_t)(b * Nn + row) * Tt + (ft - 1) * 64);
    #pragma unroll
    for (int i = 0; i < 4; ++i) {
        float4 v = *(const float4*)(src + seg * 16 + i * 4);
        float* d = &T[row * 65 + seg * 16 + i * 4];
        d[0] = v.x; d[1] = v.y; d[2] = v.z; d[3] = v.w;
    }
    __syncthreads();
    const int w = tid >> 6, lane = tid & 63;
    #pragma unroll
    for (int k = 0; k < 16; ++k) {
        int f = w * 16 + k;
        float x = T[lane * 65 + f];
        float incl = x;
        #pragma unroll
        for (int o = 1; o < 64; o <<= 1) {
            float t = __shfl_up(incl, o);
            if (lane >= o) incl += t;
        }
        float excl = incl - x;
        T[lane * 65 + f] = lane ? excl * __builtin_amdgcn_rcpf((float)lane) : 0.f;
    }
    __syncthreads();
    const int node = tid >> 2, f0 = (tid & 3) * 16;
    ushort tmp[16];
    #pragma unroll
    for (int i = 0; i < 16; ++i) tmp[i] = f2bf(T[node * 65 + f0 + i]);
    ushort* dst = agg + (size_t)(b * Nn + node) * INF + ft * 64 + f0;
    *(uint4*)dst = *(uint4*)tmp;
    *(uint4*)(dst + 8) = *(uint4*)(tmp + 8);
}

// ---------------- bf16 MFMA GEMM, 64x64 tile, BK=64, B pre-transposed ----------------
// edgeScale (transC only): cols 0-255 *= 1/sqrt(ln2); cols 256-511 -> exp(v)
// (stored as e^v so the edge kernel's softplus is log2(1+e_i*e_j): 1 transc).
__global__ __launch_bounds__(256) void k_gemm_mfma(const ushort* __restrict__ A,
                                                   const ushort* __restrict__ BT,
                                                   const float* __restrict__ bias,
                                                   ushort* __restrict__ Cb,
                                                   float* __restrict__ Cf,
                                                   int N, int K, int relu, int transC,
                                                   int edgeScale) {
    __shared__ ushort Asl[64 * 72];
    __shared__ ushort Bsl[64 * 72];   // [n][k]
    const int tid = threadIdx.x;
    const int w = tid >> 6, lane = tid & 63;
    const int quad = lane >> 4, r16 = lane & 15;
    const int m0 = blockIdx.y * 64, n0 = blockIdx.x * 64;
    const int row = tid >> 2, seg = tid & 3;
    f32x4 acc[4] = {};

    for (int k0 = 0; k0 < K; k0 += 64) {
        const ushort* ap = A + (size_t)(m0 + row) * K + k0 + seg * 16;
        uint4 a0 = ((const uint4*)ap)[0];
        uint4 a1 = ((const uint4*)ap)[1];
        *(uint4*)(Asl + row * 72 + seg * 16)     = a0;
        *(uint4*)(Asl + row * 72 + seg * 16 + 8) = a1;
        const ushort* bp = BT + (size_t)(n0 + row) * K + k0 + seg * 16;
        uint4 b0 = ((const uint4*)bp)[0];
        uint4 b1 = ((const uint4*)bp)[1];
        *(uint4*)(Bsl + row * 72 + seg * 16)     = b0;
        *(uint4*)(Bsl + row * 72 + seg * 16 + 8) = b1;
        __syncthreads();

        bf16x8 af0 = *(const bf16x8*)(Asl + (w * 16 + r16) * 72 + quad * 8);
        bf16x8 af1 = *(const bf16x8*)(Asl + (w * 16 + r16) * 72 + 32 + quad * 8);
        #pragma unroll
        for (int ns = 0; ns < 4; ++ns) {
            bf16x8 bf0 = *(const bf16x8*)(Bsl + (ns * 16 + r16) * 72 + quad * 8);
            bf16x8 bf1 = *(const bf16x8*)(Bsl + (ns * 16 + r16) * 72 + 32 + quad * 8);
            acc[ns] = __builtin_amdgcn_mfma_f32_16x16x32_bf16(af0, bf0, acc[ns], 0, 0, 0);
            acc[ns] = __builtin_amdgcn_mfma_f32_16x16x32_bf16(af1, bf1, acc[ns], 0, 0, 0);
        }
        __syncthreads();
    }

    const int row0 = m0 + w * 16 + quad * 4;
    #pragma unroll
    for (int ns = 0; ns < 4; ++ns) {
        f32x4 a = acc[ns];
        int col = n0 + ns * 16 + r16;
        float bb = bias ? bias[col] : 0.f;
        float vv[4];
        #pragma unroll
        for (int i = 0; i < 4; ++i) {
            float v = a[i] + bb;
            if (relu) v = fmaxf(v, 0.f);
            vv[i] = v;
        }
        if (transC) {
            if (edgeScale) {
                if (col < 256) {
                    #pragma unroll
                    for (int i = 0; i < 4; ++i) vv[i] *= RSQRT_LN2;
                } else if (col < 512) {
                    #pragma unroll
                    for (int i = 0; i < 4; ++i)
                        vv[i] = __builtin_amdgcn_exp2f(vv[i] * LOG2E);  // e^v
                }
            }
            *(float4*)(Cf + (size_t)col * MROWS + row0) = make_float4(vv[0], vv[1], vv[2], vv[3]);
        } else {
            #pragma unroll
            for (int i = 0; i < 4; ++i) {
                int row2 = row0 + i;
                if (Cb) Cb[(size_t)row2 * N + col] = f2bf(vv[i]);
                else    Cf[(size_t)row2 * N + col] = vv[i];
            }
        }
    }
}

// ---------------- edge kernel: whole-graph tile, 2x2 pair blocking, o-split x4 ----------------
// 512 blocks = 128 graphs x 4 o-chunks of 32. Block = 512 threads.
// REGISTER BUDGET (round-3 fix): launch_bounds min-waves 4 -> 2 (VGPR cap 128 -> 256)
// and inner unroll 4 -> 2 (in-flight LDS operands 128 -> 64 VGPRs). Round 2's combo
// forced scratch spill of the load batch inside the hot loop (+40us). Occupancy is
// grid-limited at 2 blocks/CU (16 waves) regardless; post-stage the loop is pure
// LDS+VALU with 16 independent eterm chains/thread, so 16 waves covers latency.
static __device__ __forceinline__ float et(float mA, float mB, float eA, float eB) {
    float m = mA + mB;                       // mean, pre-scaled by 1/sqrt(ln2)
    float E = eA * eB;                       // e^{vi+vj}
    float t = __builtin_amdgcn_logf(1.f + E) + EPS_T;   // softplus * log2e
    return m * m * __builtin_amdgcn_rcpf(t);
}

__global__ __launch_bounds__(512, 2) void k_edge5(const float* __restrict__ ST,
                                                  float* __restrict__ accp) {
    __shared__ float L[4][64][36];
    const int bid = blockIdx.x;
    const int b = bid >> 2, oc = bid & 3;
    const int tid = threadIdx.x;

    // stage: 4 arrays x 32 o-rows x 64 nodes (16 quads); 4 float4 per thread
    {
        const int c = (tid >> 4) & 31, q = tid & 15, n = q << 2;
        const int s0 = c ^ ((((n    ) >> 1) & 7) << 2);
        const int s1 = c ^ ((((n + 1) >> 1) & 7) << 2);
        const int s2 = c ^ ((((n + 2) >> 1) & 7) << 2);
        const int s3 = c ^ ((((n + 3) >> 1) & 7) << 2);
        #pragma unroll
        for (int arr = 0; arr < 4; ++arr) {
            float4 v = *(const float4*)&ST[(size_t)(arr * 128 + oc * 32 + c) * MROWS
                                           + b * 64 + n];
            L[arr][n + 0][s0] = v.x;
            L[arr][n + 1][s1] = v.y;
            L[arr][n + 2][s2] = v.z;
            L[arr][n + 3][s3] = v.w;
        }
    }

    // pair decode
    const bool strict = tid < 496;
    int ri0, ri1, rj0, rj1;
    if (strict) {
        int rr = tid, ci = 0;
        while (rr >= 31 - ci) { rr -= 31 - ci; ++ci; }
        int cj = ci + 1 + rr;
        ri0 = 2 * ci; ri1 = ri0 + 1;
        rj0 = 2 * cj; rj1 = rj0 + 1;
    } else {
        int d0 = (tid - 496) * 2, d1 = d0 + 1;
        ri0 = 2 * d0; rj0 = ri0 + 1;   // edge (ri0, ri0+1)
        ri1 = 2 * d1; rj1 = ri1 + 1;   // edge (ri1, ri1+1)
    }
    const float* M0 = &L[0][ri0][0]; const float* M1 = &L[0][ri1][0];
    const float* N0 = &L[1][rj0][0]; const float* N1 = &L[1][rj1][0];
    const float* E0 = &L[2][ri0][0]; const float* E1 = &L[2][ri1][0];
    const float* F0 = &L[3][rj0][0]; const float* F1 = &L[3][rj1][0];
    const int si0 = ((ri0 >> 1) & 7) << 2, si1 = ((ri1 >> 1) & 7) << 2;
    const int sj0 = ((rj0 >> 1) & 7) << 2, sj1 = ((rj1 >> 1) & 7) << 2;

    __syncthreads();

    float a00 = 0.f, a01 = 0.f, a10 = 0.f, a11 = 0.f;
    #pragma unroll 2
    for (int t = 0; t < 32; t += 4) {
        float4 m0 = *(const float4*)(M0 + (t ^ si0));
        float4 m1 = *(const float4*)(M1 + (t ^ si1));
        float4 n0 = *(const float4*)(N0 + (t ^ sj0));
        float4 n1 = *(const float4*)(N1 + (t ^ sj1));
        float4 e0 = *(const float4*)(E0 + (t ^ si0));
        float4 e1 = *(const float4*)(E1 + (t ^ si1));
        float4 f0 = *(const float4*)(F0 + (t ^ sj0));
        float4 f1 = *(const float4*)(F1 + (t ^ sj1));
        a00 += et(m0.x,n0.x,e0.x,f0.x) + et(m0.y,n0.y,e0.y,f0.y)
             + et(m0.z,n0.z,e0.z,f0.z) + et(m0.w,n0.w,e0.w,f0.w);
        a11 += et(m1.x,n1.x,e1.x,f1.x) + et(m1.y,n1.y,e1.y,f1.y)
             + et(m1.z,n1.z,e1.z,f1.z) + et(m1.w,n1.w,e1.w,f1.w);
        if (strict) {
            a01 += et(m0.x,n1.x,e0.x,f1.x) + et(m0.y,n1.y,e0.y,f1.y)
                 + et(m0.z,n1.z,e0.z,f1.z) + et(m0.w,n1.w,e0.w,f1.w);
            a10 += et(m1.x,n0.x,e1.x,f0.x) + et(m1.y,n0.y,e1.y,f0.y)
                 + et(m1.z,n0.z,e1.z,f0.z) + et(m1.w,n0.w,e1.w,f0.w);
        }
    }

    float* ap = accp + (size_t)oc * TOTE + (size_t)b * Ee;
    if (strict) {
        int e0i = (ri0 * (127 - ri0)) / 2 + (rj0 - ri0 - 1);
        int e1i = (ri1 * (127 - ri1)) / 2 + (rj0 - ri1 - 1);
        ap[e0i] = a00; ap[e0i + 1] = a01;
        ap[e1i] = a10; ap[e1i + 1] = a11;
    } else {
        ap[(ri0 * (127 - ri0)) / 2] = a00;
        ap[(ri1 * (127 - ri1)) / 2] = a11;
    }
}

// ---------------- gumbel/sigmoid numerator + softmax denominator ----------------
__global__ __launch_bounds__(256) void k_den(const float* __restrict__ ST,
                                             const float* __restrict__ gu,
                                             float* __restrict__ numer,
                                             unsigned* __restrict__ red) {
    __shared__ float sred[4];
    const int tid = threadIdx.x;
    int idx = blockIdx.x * 256 + tid;
    int b = idx >> 12, rem = idx & 4095;
    int r = rem >> 6, c = rem & 63;
    float en = 0.f;
    if (c > r) {
        int e = b * Ee + (r * (127 - r)) / 2 + (c - r - 1);
        float wr = ST[(size_t)512 * MROWS + b * 64 + r]
                 + ST[(size_t)513 * MROWS + b * 64 + c];
        float w  = __builtin_amdgcn_rcpf(1.f + __expf(-wr));
        float g  = -__logf(-__logf(gu[e]));
        en = __expf((w + g) * 2.0f);           // exp(logit/T), logit <= ~36: safe
        numer[e] = en;
    }
    float s = en;
    #pragma unroll
    for (int o = 32; o; o >>= 1) s += __shfl_down(s, o);
    if ((tid & 63) == 0) sred[tid >> 6] = s;
    __syncthreads();
    if (tid == 0) atomicAdd((float*)&red[1], sred[0] + sred[1] + sred[2] + sred[3]);
}

// ---------------- final scatter: combine acc partials, normalize, zero-fill ----------------
__global__ void k_out(const float* __restrict__ accp, const float* __restrict__ numer,
                      const unsigned* __restrict__ red, float* __restrict__ out) {
    int idx = blockIdx.x * 256 + threadIdx.x;
    if (idx >= Bg * Nn * Nn) return;
    int b = idx >> 12;
    int rem = idx & 4095;
    int r = rem >> 6, c = rem & 63;
    float v = 0.f;
    if (c > r) {
        int e = b * Ee + (r * (127 - r)) / 2 + (c - r - 1);
        float a = accp[e] + accp[TOTE + e] + accp[2 * TOTE + e] + accp[3 * TOTE + e];
        float se = __expf(a * (-1.f / 256.f));
        float Sinv = __builtin_amdgcn_rcpf(((const float*)red)[1]);
        v = se * numer[e] * Sinv;
    }
    out[idx] = v;
}

extern "C" void kernel_launch(void* const* d_in, const int* in_sizes, int n_in,
                              void* d_out, int out_size, void* d_ws, size_t ws_size,
                              hipStream_t stream) {
    const float* topo = (const float*)d_in[0];
    const float* temp = (const float*)d_in[1];
    const float* gu   = (const float*)d_in[2];
    const float* Wg   = (const float*)d_in[3];
    const float* bg   = (const float*)d_in[4];
    const float* Wm   = (const float*)d_in[5];
    const float* bm   = (const float*)d_in[6];
    const float* Wv   = (const float*)d_in[7];
    const float* bv   = (const float*)d_in[8];
    const float* Ww   = (const float*)d_in[9];
    const float* bw   = (const float*)d_in[10];
    float* out = (float*)d_out;

    char* ws = (char*)d_ws;
    size_t off = 0;
    auto carve = [&](size_t bytes) { char* p = ws + off; off = (off + bytes + 255) & ~(size_t)255; return p; };

    // r1 hosts aggb (bf16, 5.2 MB) pre-GEMM1, then S_T[576][8192] f32 (18.9 MB).
    char*   r1    = carve((size_t)SCOLS * MROWS * 4);
    float*  ST    = (float*)r1;
    ushort* aggb  = (ushort*)r1;
    ushort* hb    = (ushort*)carve((size_t)MROWS * Hd * 2);      // 4.19 MB
    ushort* WgbT  = (ushort*)carve((size_t)INF * Hd * 2);        // 0.16 MB
    ushort* WcatT = (ushort*)carve((size_t)Hd * SCOLS * 2);      // 0.29 MB
    float*  ebias = (float*)carve((size_t)SCOLS * 4);
    float*  numer = (float*)carve((size_t)TOTE * 4);             // 1.03 MB
    float*  accp  = (float*)carve((size_t)4 * TOTE * 4);         // 4.13 MB
    unsigned* red = (unsigned*)carve(256);

    k_prep<<<(CVT_N + PACK_N + SCOLS + 255) / 256, 256, 0, stream>>>(
        Wg, Wm, Wv, Ww, bm, bv, bw, WgbT, WcatT, ebias, red);
    k_agg<<<dim3(Bg, INF / 64), 256, 0, stream>>>(topo, temp, aggb);
    // GEMM1: hb[8192,256] = relu(aggb[8192,320] @ WgbT^T + bg)
    k_gemm_mfma<<<dim3(Hd / 64, MROWS / 64), 256, 0, stream>>>(
        aggb, WgbT, bg, hb, nullptr, Hd, INF, 1, 0, 0);
    // GEMM2: ST[576][8192] = colxf((hb[8192,256] @ WcatT^T + ebias))^T
    k_gemm_mfma<<<dim3(SCOLS / 64, MROWS / 64), 256, 0, stream>>>(
        hb, WcatT, ebias, nullptr, ST, SCOLS, Hd, 0, 1, 1);
    k_edge5<<<Bg * 4, 512, 0, stream>>>(ST, accp);
    k_den<<<(Bg * Nn * Nn) / 256, 256, 0, stream>>>(ST, gu, numer, red);
    k_out<<<(Bg * Nn * Nn + 255) / 256, 256, 0, stream>>>(accp, numer, red, out);
}

// Round 4
// 134.997 us; speedup vs baseline: 1.3144x; 1.1659x over previous
//
#include <hip/hip_runtime.h>
#include <hip/hip_bf16.h>
#include <math.h>

#define Bg   128
#define Nn   64
#define Tt   256
#define INF  320      // Nn + Tt
#define Hd   256
#define OUTD 128
#define Ee   2016     // Nn*(Nn-1)/2
#define TOTE (Bg*Ee)  // 258048
#define SCOLS 576     // padded 514 -> 9*64 so GEMM2 tiles exactly
#define MROWS 8192    // Bg*Nn

#define RSQRT_LN2 1.2011224087864498f   // 1/sqrt(ln2): mean cols pre-scale
#define LOG2E     1.4426950408889634f
#define EPS_T     1.45719e-6f           // 1.01e-6 * log2e

typedef __attribute__((ext_vector_type(8))) short bf16x8;
typedef __attribute__((ext_vector_type(4))) float f32x4;

static __device__ __forceinline__ ushort f2bf(float v) {
    __hip_bfloat16 h = __float2bfloat16(v);
    return *(ushort*)&h;
}

// ---------------- prep: WgT->bf16, packed WcatT->bf16, ebias, red init ----------------
#define CVT_N (INF * Hd)                  // 81920
#define PACK_N (Hd * SCOLS)               // 147456
__global__ void k_prep(const float* __restrict__ Wg, const float* __restrict__ Wm,
                       const float* __restrict__ Wv, const float* __restrict__ Ww,
                       const float* __restrict__ bm, const float* __restrict__ bv,
                       const float* __restrict__ bw,
                       ushort* __restrict__ WgbT, ushort* __restrict__ WcatT,
                       float* __restrict__ ebias, unsigned* __restrict__ red) {
    int idx = blockIdx.x * 256 + threadIdx.x;
    if (idx == 0) { red[0] = 0u; red[1] = 0u; }
    if (idx < CVT_N) {
        int n = idx / INF, k = idx - n * INF;
        WgbT[idx] = f2bf(Wg[k * Hd + n]);
        return;
    }
    idx -= CVT_N;
    if (idx < PACK_N) {
        int n = idx / Hd, k = idx - n * Hd;   // n = output col, k = reduction
        float v = 0.f;
        if (n < 128)       v = Wm[k * 128 + n];
        else if (n < 256)  v = Wm[(256 + k) * 128 + (n - 128)];
        else if (n < 384)  v = Wv[k * 128 + (n - 256)];
        else if (n < 512)  v = Wv[(256 + k) * 128 + (n - 384)];
        else if (n == 512) v = Ww[k];
        else if (n == 513) v = Ww[256 + k];
        WcatT[idx] = f2bf(v);
        return;
    }
    idx -= PACK_N;
    if (idx >= SCOLS) return;
    float e = 0.f;
    if (idx < 128)                    e = bm[idx];
    else if (idx >= 256 && idx < 384) e = bv[idx - 256];
    else if (idx == 512)              e = bw[0];
    ebias[idx] = e;
}

// ---------------- prefix-mean aggregation: LDS-tiled coalesced scan ----------------
__global__ __launch_bounds__(256) void k_agg(const float* __restrict__ topo,
                                             const float* __restrict__ temp,
                                             ushort* __restrict__ agg) {
    __shared__ float T[64 * 65];
    const int b = blockIdx.x, ft = blockIdx.y;
    const int tid = threadIdx.x;
    const int row = tid >> 2, seg = tid & 3;
    const float* src = (ft == 0) ? (topo + (size_t)(b * Nn + row) * Nn)
                                 : (temp + (size_t)(b * Nn + row) * Tt + (ft - 1) * 64);
    #pragma unroll
    for (int i = 0; i < 4; ++i) {
        float4 v = *(const float4*)(src + seg * 16 + i * 4);
        float* d = &T[row * 65 + seg * 16 + i * 4];
        d[0] = v.x; d[1] = v.y; d[2] = v.z; d[3] = v.w;
    }
    __syncthreads();
    const int w = tid >> 6, lane = tid & 63;
    #pragma unroll
    for (int k = 0; k < 16; ++k) {
        int f = w * 16 + k;
        float x = T[lane * 65 + f];
        float incl = x;
        #pragma unroll
        for (int o = 1; o < 64; o <<= 1) {
            float t = __shfl_up(incl, o);
            if (lane >= o) incl += t;
        }
        float excl = incl - x;
        T[lane * 65 + f] = lane ? excl * __builtin_amdgcn_rcpf((float)lane) : 0.f;
    }
    __syncthreads();
    const int node = tid >> 2, f0 = (tid & 3) * 16;
    ushort tmp[16];
    #pragma unroll
    for (int i = 0; i < 16; ++i) tmp[i] = f2bf(T[node * 65 + f0 + i]);
    ushort* dst = agg + (size_t)(b * Nn + node) * INF + ft * 64 + f0;
    *(uint4*)dst = *(uint4*)tmp;
    *(uint4*)(dst + 8) = *(uint4*)(tmp + 8);
}

// ---------------- bf16 MFMA GEMM, 64x64 tile, BK=64, B pre-transposed ----------------
// edgeScale (transC only): cols 0-255 *= 1/sqrt(ln2); cols 256-511 -> exp(v)
// (stored as e^v so the edge kernel's softplus is log2(1+Ei*Ej): 2 transc/eterm).
__global__ __launch_bounds__(256) void k_gemm_mfma(const ushort* __restrict__ A,
                                                   const ushort* __restrict__ BT,
                                                   const float* __restrict__ bias,
                                                   ushort* __restrict__ Cb,
                                                   float* __restrict__ Cf,
                                                   int N, int K, int relu, int transC,
                                                   int edgeScale) {
    __shared__ ushort Asl[64 * 72];
    __shared__ ushort Bsl[64 * 72];   // [n][k]
    const int tid = threadIdx.x;
    const int w = tid >> 6, lane = tid & 63;
    const int quad = lane >> 4, r16 = lane & 15;
    const int m0 = blockIdx.y * 64, n0 = blockIdx.x * 64;
    const int row = tid >> 2, seg = tid & 3;
    f32x4 acc[4] = {};

    for (int k0 = 0; k0 < K; k0 += 64) {
        const ushort* ap = A + (size_t)(m0 + row) * K + k0 + seg * 16;
        uint4 a0 = ((const uint4*)ap)[0];
        uint4 a1 = ((const uint4*)ap)[1];
        *(uint4*)(Asl + row * 72 + seg * 16)     = a0;
        *(uint4*)(Asl + row * 72 + seg * 16 + 8) = a1;
        const ushort* bp = BT + (size_t)(n0 + row) * K + k0 + seg * 16;
        uint4 b0 = ((const uint4*)bp)[0];
        uint4 b1 = ((const uint4*)bp)[1];
        *(uint4*)(Bsl + row * 72 + seg * 16)     = b0;
        *(uint4*)(Bsl + row * 72 + seg * 16 + 8) = b1;
        __syncthreads();

        bf16x8 af0 = *(const bf16x8*)(Asl + (w * 16 + r16) * 72 + quad * 8);
        bf16x8 af1 = *(const bf16x8*)(Asl + (w * 16 + r16) * 72 + 32 + quad * 8);
        #pragma unroll
        for (int ns = 0; ns < 4; ++ns) {
            bf16x8 bf0 = *(const bf16x8*)(Bsl + (ns * 16 + r16) * 72 + quad * 8);
            bf16x8 bf1 = *(const bf16x8*)(Bsl + (ns * 16 + r16) * 72 + 32 + quad * 8);
            acc[ns] = __builtin_amdgcn_mfma_f32_16x16x32_bf16(af0, bf0, acc[ns], 0, 0, 0);
            acc[ns] = __builtin_amdgcn_mfma_f32_16x16x32_bf16(af1, bf1, acc[ns], 0, 0, 0);
        }
        __syncthreads();
    }

    const int row0 = m0 + w * 16 + quad * 4;
    #pragma unroll
    for (int ns = 0; ns < 4; ++ns) {
        f32x4 a = acc[ns];
        int col = n0 + ns * 16 + r16;
        float bb = bias ? bias[col] : 0.f;
        float vv[4];
        #pragma unroll
        for (int i = 0; i < 4; ++i) {
            float v = a[i] + bb;
            if (relu) v = fmaxf(v, 0.f);
            vv[i] = v;
        }
        if (transC) {
            if (edgeScale) {
                if (col < 256) {
                    #pragma unroll
                    for (int i = 0; i < 4; ++i) vv[i] *= RSQRT_LN2;
                } else if (col < 512) {
                    #pragma unroll
                    for (int i = 0; i < 4; ++i)
                        vv[i] = __builtin_amdgcn_exp2f(vv[i] * LOG2E);  // e^v
                }
            }
            *(float4*)(Cf + (size_t)col * MROWS + row0) = make_float4(vv[0], vv[1], vv[2], vv[3]);
        } else {
            #pragma unroll
            for (int i = 0; i < 4; ++i) {
                int row2 = row0 + i;
                if (Cb) Cb[(size_t)row2 * N + col] = f2bf(vv[i]);
                else    Cf[(size_t)row2 * N + col] = vv[i];
            }
        }
    }
}

// ---------------- fused edge kernel -> numer + denominator atomic ----------------
// ROUND-1 STRUCTURE (measured best: 135.9 total). 1280 blocks = 128 graphs x 10
// group-pairs, XCD-swizzled; two o-phases of 64 (LDS 17424B); diagonal tiles pack
// 120 valid pairs into threads 0..119.
// ROUND-4 CHANGE: var rows of ST now hold E = e^v (GEMM2 epilogue), so
// eterm = m'^2 * rcp(log2(1+Ei*Ej) + eps') == m^2/(softplus(v)+1.01e-6):
// 2 transcendentals instead of 3, no fabs/max -> ~30% less VALU issue on the
// dominant (VALU-issue-bound, round-0 VALUBusy 60%) kernel.
static __device__ __forceinline__ float et(float mA, float mB, float eA, float eB) {
    float m = mA + mB;                       // mean, pre-scaled by 1/sqrt(ln2)
    float E = eA * eB;                       // e^{vi+vj}
    float t = __builtin_amdgcn_logf(1.f + E) + EPS_T;   // softplus * log2e
    return m * m * __builtin_amdgcn_rcpf(t);
}

__global__ __launch_bounds__(256, 8) void k_edge4(const float* __restrict__ ST,
                                                  const float* __restrict__ gu,
                                                  float* __restrict__ numer,
                                                  unsigned* __restrict__ red) {
    __shared__ float L[4][16][68];
    __shared__ float sred[4];
    // XCD swizzle: bid%8 = XCD (round-robin dispatch); give each XCD 16 whole graphs.
    const int bid = blockIdx.x;
    const int xcd = bid & 7, k = bid >> 3;          // k in 0..159
    const int b = xcd * 16 + k / 10;
    const int p = k - (k / 10) * 10;
    const int G0v[10] = {0,0,0,0,1,1,1,2,2,3};
    const int G1v[10] = {0,1,2,3,1,2,3,2,3,3};
    const int g0 = G0v[p], g1 = G1v[p];
    const int tid = threadIdx.x;

    // pair decode: off-diag tiles use all 256 threads; diagonal tiles pack the
    // 120 upper-tri pairs into threads 0..119.
    int i, j;
    bool valid;
    if (g0 != g1) {
        i = tid >> 4; j = tid & 15; valid = true;
    } else {
        valid = tid < 120;
        int ii = 0, rr = tid;
        if (valid) { while (rr >= 15 - ii) { rr -= 15 - ii; ++ii; } }
        i = valid ? ii : 0;
        j = valid ? (ii + 1 + rr) : 1;
    }

    const int c = tid >> 2, nq = tid & 3;   // stage coords: o-row, node-quad
    float acc = 0.f;
    #pragma unroll
    for (int h = 0; h < 2; ++h) {
        if (h) __syncthreads();             // drain phase-0 reads before restage
        #pragma unroll
        for (int arr = 0; arr < 4; ++arr) {
            const int g = (arr & 1) ? g1 : g0;
            float4 v = *(const float4*)&ST[(size_t)((arr << 7) + (h << 6) + c) * MROWS
                                           + b * 64 + (g << 4) + (nq << 2)];
            L[arr][nq * 4 + 0][c] = v.x;
            L[arr][nq * 4 + 1][c] = v.y;
            L[arr][nq * 4 + 2][c] = v.z;
            L[arr][nq * 4 + 3][c] = v.w;
        }
        __syncthreads();
        if (valid) {
            #pragma unroll 4
            for (int t = 0; t < 64; t += 4) {
                float4 mi = *(const float4*)&L[0][i][t];
                float4 mj = *(const float4*)&L[1][j][t];
                float4 ei = *(const float4*)&L[2][i][t];
                float4 ej = *(const float4*)&L[3][j][t];
                acc += et(mi.x, mj.x, ei.x, ej.x);
                acc += et(mi.y, mj.y, ei.y, ej.y);
                acc += et(mi.z, mj.z, ei.z, ej.z);
                acc += et(mi.w, mj.w, ei.w, ej.w);
            }
        }
    }

    const int ni = g0 * 16 + i, nj = g1 * 16 + j;
    float en = 0.f;
    if (valid) {                            // valid implies ni < nj by construction
        int e = b * Ee + (ni * (127 - ni)) / 2 + (nj - ni - 1);
        float se = __expf(acc * (-1.f / 256.f));   // acc == sum m^2/(sp+1.01e-6) exactly
        float wr = ST[(size_t)512 * MROWS + b * 64 + ni]
                 + ST[(size_t)513 * MROWS + b * 64 + nj];   // w rows unscaled
        float w  = __builtin_amdgcn_rcpf(1.f + __expf(-wr));
        float g  = -__logf(-__logf(gu[e]));
        en = __expf((w + g) * 2.0f);               // exp(logit), logit <= ~36: safe
        numer[e] = se * en;
    }
    // block reduce en for the softmax denominator: wave shuffle + 4-slot LDS
    #pragma unroll
    for (int o = 32; o; o >>= 1) en += __shfl_down(en, o);
    if ((tid & 63) == 0) sred[tid >> 6] = en;
    __syncthreads();
    if (tid == 0) atomicAdd((float*)&red[1], sred[0] + sred[1] + sred[2] + sred[3]);
}

// ---------------- final scatter (also zero-fills) ----------------
__global__ void k_out(const float* __restrict__ numer, const unsigned* __restrict__ red,
                      float* __restrict__ out) {
    int idx = blockIdx.x * 256 + threadIdx.x;
    if (idx >= Bg * Nn * Nn) return;
    int b = idx >> 12;
    int rem = idx & 4095;
    int r = rem >> 6, c = rem & 63;
    float v = 0.f;
    if (c > r) {
        int e = b * Ee + (r * (127 - r)) / 2 + (c - r - 1);
        float Sinv = __builtin_amdgcn_rcpf(((const float*)red)[1]);
        v = numer[e] * Sinv;
    }
    out[idx] = v;
}

extern "C" void kernel_launch(void* const* d_in, const int* in_sizes, int n_in,
                              void* d_out, int out_size, void* d_ws, size_t ws_size,
                              hipStream_t stream) {
    const float* topo = (const float*)d_in[0];
    const float* temp = (const float*)d_in[1];
    const float* gu   = (const float*)d_in[2];
    const float* Wg   = (const float*)d_in[3];
    const float* bg   = (const float*)d_in[4];
    const float* Wm   = (const float*)d_in[5];
    const float* bm   = (const float*)d_in[6];
    const float* Wv   = (const float*)d_in[7];
    const float* bv   = (const float*)d_in[8];
    const float* Ww   = (const float*)d_in[9];
    const float* bw   = (const float*)d_in[10];
    float* out = (float*)d_out;

    char* ws = (char*)d_ws;
    size_t off = 0;
    auto carve = [&](size_t bytes) { char* p = ws + off; off = (off + bytes + 255) & ~(size_t)255; return p; };

    // r1 hosts aggb (bf16, 5.2 MB) pre-GEMM1, then S_T[576][8192] f32 (18.9 MB).
    char*   r1    = carve((size_t)SCOLS * MROWS * 4);
    float*  ST    = (float*)r1;
    ushort* aggb  = (ushort*)r1;
    ushort* hb    = (ushort*)carve((size_t)MROWS * Hd * 2);      // 4.19 MB
    ushort* WgbT  = (ushort*)carve((size_t)INF * Hd * 2);        // 0.16 MB
    ushort* WcatT = (ushort*)carve((size_t)Hd * SCOLS * 2);      // 0.29 MB
    float*  ebias = (float*)carve((size_t)SCOLS * 4);
    float*  numer = (float*)carve((size_t)TOTE * 4);             // 1.03 MB
    unsigned* red = (unsigned*)carve(256);

    k_prep<<<(CVT_N + PACK_N + SCOLS + 255) / 256, 256, 0, stream>>>(
        Wg, Wm, Wv, Ww, bm, bv, bw, WgbT, WcatT, ebias, red);
    k_agg<<<dim3(Bg, INF / 64), 256, 0, stream>>>(topo, temp, aggb);
    // GEMM1: hb[8192,256] = relu(aggb[8192,320] @ WgbT^T + bg)
    k_gemm_mfma<<<dim3(Hd / 64, MROWS / 64), 256, 0, stream>>>(
        aggb, WgbT, bg, hb, nullptr, Hd, INF, 1, 0, 0);
    // GEMM2: ST[576][8192] = colxf((hb[8192,256] @ WcatT^T + ebias))^T
    k_gemm_mfma<<<dim3(SCOLS / 64, MROWS / 64), 256, 0, stream>>>(
        hb, WcatT, ebias, nullptr, ST, SCOLS, Hd, 0, 1, 1);
    k_edge4<<<Bg * 10, 256, 0, stream>>>(ST, gu, numer, red);
    k_out<<<(Bg * Nn * Nn + 255) / 256, 256, 0, stream>>>(numer, red, out);
}

// Round 5
// 133.498 us; speedup vs baseline: 1.3292x; 1.0112x over previous
//
#include <hip/hip_runtime.h>
#include <hip/hip_bf16.h>
#include <math.h>

#define Bg   128
#define Nn   64
#define Tt   256
#define INF  320      // Nn + Tt
#define Hd   256
#define OUTD 128
#define Ee   2016     // Nn*(Nn-1)/2
#define TOTE (Bg*Ee)  // 258048
#define SCOLS 576     // padded 514 -> 9*64 so GEMM2 tiles exactly
#define MROWS 8192    // Bg*Nn

#define RSQRT_LN2 1.2011224087864498f   // 1/sqrt(ln2): mean cols pre-scale
#define LOG2E     1.4426950408889634f
#define EPS_T     1.45719e-6f           // 1.01e-6 * log2e

typedef __attribute__((ext_vector_type(8))) short bf16x8;
typedef __attribute__((ext_vector_type(4))) float f32x4;

static __device__ __forceinline__ ushort f2bf(float v) {
    __hip_bfloat16 h = __float2bfloat16(v);
    return *(ushort*)&h;
}

// ---------------- prep: WgT->bf16, packed WcatT->bf16, ebias, red init ----------------
#define CVT_N (INF * Hd)                  // 81920
#define PACK_N (Hd * SCOLS)               // 147456
__global__ void k_prep(const float* __restrict__ Wg, const float* __restrict__ Wm,
                       const float* __restrict__ Wv, const float* __restrict__ Ww,
                       const float* __restrict__ bm, const float* __restrict__ bv,
                       const float* __restrict__ bw,
                       ushort* __restrict__ WgbT, ushort* __restrict__ WcatT,
                       float* __restrict__ ebias, unsigned* __restrict__ red) {
    int idx = blockIdx.x * 256 + threadIdx.x;
    if (idx == 0) { red[0] = 0u; red[1] = 0u; }
    if (idx < CVT_N) {
        int n = idx / INF, k = idx - n * INF;
        WgbT[idx] = f2bf(Wg[k * Hd + n]);
        return;
    }
    idx -= CVT_N;
    if (idx < PACK_N) {
        int n = idx / Hd, k = idx - n * Hd;   // n = output col, k = reduction
        float v = 0.f;
        if (n < 128)       v = Wm[k * 128 + n];
        else if (n < 256)  v = Wm[(256 + k) * 128 + (n - 128)];
        else if (n < 384)  v = Wv[k * 128 + (n - 256)];
        else if (n < 512)  v = Wv[(256 + k) * 128 + (n - 384)];
        else if (n == 512) v = Ww[k];
        else if (n == 513) v = Ww[256 + k];
        WcatT[idx] = f2bf(v);
        return;
    }
    idx -= PACK_N;
    if (idx >= SCOLS) return;
    float e = 0.f;
    if (idx < 128)                    e = bm[idx];
    else if (idx >= 256 && idx < 384) e = bv[idx - 256];
    else if (idx == 512)              e = bw[0];
    ebias[idx] = e;
}

// ---------------- prefix-mean aggregation: LDS-tiled coalesced scan ----------------
__global__ __launch_bounds__(256) void k_agg(const float* __restrict__ topo,
                                             const float* __restrict__ temp,
                                             ushort* __restrict__ agg) {
    __shared__ float T[64 * 65];
    const int b = blockIdx.x, ft = blockIdx.y;
    const int tid = threadIdx.x;
    const int row = tid >> 2, seg = tid & 3;
    const float* src = (ft == 0) ? (topo + (size_t)(b * Nn + row) * Nn)
                                 : (temp + (size_t)(b * Nn + row) * Tt + (ft - 1) * 64);
    #pragma unroll
    for (int i = 0; i < 4; ++i) {
        float4 v = *(const float4*)(src + seg * 16 + i * 4);
        float* d = &T[row * 65 + seg * 16 + i * 4];
        d[0] = v.x; d[1] = v.y; d[2] = v.z; d[3] = v.w;
    }
    __syncthreads();
    const int w = tid >> 6, lane = tid & 63;
    #pragma unroll
    for (int k = 0; k < 16; ++k) {
        int f = w * 16 + k;
        float x = T[lane * 65 + f];
        float incl = x;
        #pragma unroll
        for (int o = 1; o < 64; o <<= 1) {
            float t = __shfl_up(incl, o);
            if (lane >= o) incl += t;
        }
        float excl = incl - x;
        T[lane * 65 + f] = lane ? excl * __builtin_amdgcn_rcpf((float)lane) : 0.f;
    }
    __syncthreads();
    const int node = tid >> 2, f0 = (tid & 3) * 16;
    ushort tmp[16];
    #pragma unroll
    for (int i = 0; i < 16; ++i) tmp[i] = f2bf(T[node * 65 + f0 + i]);
    ushort* dst = agg + (size_t)(b * Nn + node) * INF + ft * 64 + f0;
    *(uint4*)dst = *(uint4*)tmp;
    *(uint4*)(dst + 8) = *(uint4*)(tmp + 8);
}

// ---------------- bf16 MFMA GEMM, 64x64 tile, BK=64, B pre-transposed ----------------
// edgeScale (transC only): cols 0-255 *= 1/sqrt(ln2); cols 256-511 -> exp(v)
// (stored as e^v so the edge kernel's softplus is log2(1+Ei*Ej): 2 transc/eterm).
__global__ __launch_bounds__(256) void k_gemm_mfma(const ushort* __restrict__ A,
                                                   const ushort* __restrict__ BT,
                                                   const float* __restrict__ bias,
                                                   ushort* __restrict__ Cb,
                                                   float* __restrict__ Cf,
                                                   int N, int K, int relu, int transC,
                                                   int edgeScale) {
    __shared__ ushort Asl[64 * 72];
    __shared__ ushort Bsl[64 * 72];   // [n][k]
    const int tid = threadIdx.x;
    const int w = tid >> 6, lane = tid & 63;
    const int quad = lane >> 4, r16 = lane & 15;
    const int m0 = blockIdx.y * 64, n0 = blockIdx.x * 64;
    const int row = tid >> 2, seg = tid & 3;
    f32x4 acc[4] = {};

    for (int k0 = 0; k0 < K; k0 += 64) {
        const ushort* ap = A + (size_t)(m0 + row) * K + k0 + seg * 16;
        uint4 a0 = ((const uint4*)ap)[0];
        uint4 a1 = ((const uint4*)ap)[1];
        *(uint4*)(Asl + row * 72 + seg * 16)     = a0;
        *(uint4*)(Asl + row * 72 + seg * 16 + 8) = a1;
        const ushort* bp = BT + (size_t)(n0 + row) * K + k0 + seg * 16;
        uint4 b0 = ((const uint4*)bp)[0];
        uint4 b1 = ((const uint4*)bp)[1];
        *(uint4*)(Bsl + row * 72 + seg * 16)     = b0;
        *(uint4*)(Bsl + row * 72 + seg * 16 + 8) = b1;
        __syncthreads();

        bf16x8 af0 = *(const bf16x8*)(Asl + (w * 16 + r16) * 72 + quad * 8);
        bf16x8 af1 = *(const bf16x8*)(Asl + (w * 16 + r16) * 72 + 32 + quad * 8);
        #pragma unroll
        for (int ns = 0; ns < 4; ++ns) {
            bf16x8 bf0 = *(const bf16x8*)(Bsl + (ns * 16 + r16) * 72 + quad * 8);
            bf16x8 bf1 = *(const bf16x8*)(Bsl + (ns * 16 + r16) * 72 + 32 + quad * 8);
            acc[ns] = __builtin_amdgcn_mfma_f32_16x16x32_bf16(af0, bf0, acc[ns], 0, 0, 0);
            acc[ns] = __builtin_amdgcn_mfma_f32_16x16x32_bf16(af1, bf1, acc[ns], 0, 0, 0);
        }
        __syncthreads();
    }

    const int row0 = m0 + w * 16 + quad * 4;
    #pragma unroll
    for (int ns = 0; ns < 4; ++ns) {
        f32x4 a = acc[ns];
        int col = n0 + ns * 16 + r16;
        float bb = bias ? bias[col] : 0.f;
        float vv[4];
        #pragma unroll
        for (int i = 0; i < 4; ++i) {
            float v = a[i] + bb;
            if (relu) v = fmaxf(v, 0.f);
            vv[i] = v;
        }
        if (transC) {
            if (edgeScale) {
                if (col < 256) {
                    #pragma unroll
                    for (int i = 0; i < 4; ++i) vv[i] *= RSQRT_LN2;
                } else if (col < 512) {
                    #pragma unroll
                    for (int i = 0; i < 4; ++i)
                        vv[i] = __builtin_amdgcn_exp2f(vv[i] * LOG2E);  // e^v
                }
            }
            *(float4*)(Cf + (size_t)col * MROWS + row0) = make_float4(vv[0], vv[1], vv[2], vv[3]);
        } else {
            #pragma unroll
            for (int i = 0; i < 4; ++i) {
                int row2 = row0 + i;
                if (Cb) Cb[(size_t)row2 * N + col] = f2bf(vv[i]);
                else    Cf[(size_t)row2 * N + col] = vv[i];
            }
        }
    }
}

// ---------------- fused edge kernel -> numer + denominator atomic ----------------
// ROUND-1 STRUCTURE. 1280 blocks = 128 graphs x 10 group-pairs, XCD-swizzled;
// two o-phases of 64 (LDS 17424B); diagonal tiles pack 120 valid pairs.
// ROUND-5 FIX: __launch_bounds__ min-waves 8 -> 4. The (256,8) cap forced
// VGPR_Count=32 (seen in round-4 counters) -> the 16-float4 load batch of the
// unrolled loop couldn't be held in registers, serializing ds_reads and exposing
// ~120cy LDS latency per mini-batch (VALUBusy 59%, transc cut ineffective).
// Cap 128 lets the compiler batch loads; occupancy RISES (floor(512/VGPR) ~4-5
// waves/SIMD vs measured 30%) since grid gives 5 blocks/CU and LDS permits 8.
static __device__ __forceinline__ float et(float mA, float mB, float eA, float eB) {
    float m = mA + mB;                       // mean, pre-scaled by 1/sqrt(ln2)
    float E = eA * eB;                       // e^{vi+vj}
    float t = __builtin_amdgcn_logf(1.f + E) + EPS_T;   // softplus * log2e
    return m * m * __builtin_amdgcn_rcpf(t);
}

__global__ __launch_bounds__(256, 4) void k_edge4(const float* __restrict__ ST,
                                                  const float* __restrict__ gu,
                                                  float* __restrict__ numer,
                                                  unsigned* __restrict__ red) {
    __shared__ float L[4][16][68];
    __shared__ float sred[4];
    // XCD swizzle: bid%8 = XCD (round-robin dispatch); give each XCD 16 whole graphs.
    const int bid = blockIdx.x;
    const int xcd = bid & 7, k = bid >> 3;          // k in 0..159
    const int b = xcd * 16 + k / 10;
    const int p = k - (k / 10) * 10;
    const int G0v[10] = {0,0,0,0,1,1,1,2,2,3};
    const int G1v[10] = {0,1,2,3,1,2,3,2,3,3};
    const int g0 = G0v[p], g1 = G1v[p];
    const int tid = threadIdx.x;

    // pair decode: off-diag tiles use all 256 threads; diagonal tiles pack the
    // 120 upper-tri pairs into threads 0..119.
    int i, j;
    bool valid;
    if (g0 != g1) {
        i = tid >> 4; j = tid & 15; valid = true;
    } else {
        valid = tid < 120;
        int ii = 0, rr = tid;
        if (valid) { while (rr >= 15 - ii) { rr -= 15 - ii; ++ii; } }
        i = valid ? ii : 0;
        j = valid ? (ii + 1 + rr) : 1;
    }

    const int c = tid >> 2, nq = tid & 3;   // stage coords: o-row, node-quad
    float acc = 0.f;
    #pragma unroll
    for (int h = 0; h < 2; ++h) {
        if (h) __syncthreads();             // drain phase-0 reads before restage
        #pragma unroll
        for (int arr = 0; arr < 4; ++arr) {
            const int g = (arr & 1) ? g1 : g0;
            float4 v = *(const float4*)&ST[(size_t)((arr << 7) + (h << 6) + c) * MROWS
                                           + b * 64 + (g << 4) + (nq << 2)];
            L[arr][nq * 4 + 0][c] = v.x;
            L[arr][nq * 4 + 1][c] = v.y;
            L[arr][nq * 4 + 2][c] = v.z;
            L[arr][nq * 4 + 3][c] = v.w;
        }
        __syncthreads();
        if (valid) {
            #pragma unroll 4
            for (int t = 0; t < 64; t += 4) {
                float4 mi = *(const float4*)&L[0][i][t];
                float4 mj = *(const float4*)&L[1][j][t];
                float4 ei = *(const float4*)&L[2][i][t];
                float4 ej = *(const float4*)&L[3][j][t];
                acc += et(mi.x, mj.x, ei.x, ej.x);
                acc += et(mi.y, mj.y, ei.y, ej.y);
                acc += et(mi.z, mj.z, ei.z, ej.z);
                acc += et(mi.w, mj.w, ei.w, ej.w);
            }
        }
    }

    const int ni = g0 * 16 + i, nj = g1 * 16 + j;
    float en = 0.f;
    if (valid) {                            // valid implies ni < nj by construction
        int e = b * Ee + (ni * (127 - ni)) / 2 + (nj - ni - 1);
        float se = __expf(acc * (-1.f / 256.f));   // acc == sum m^2/(sp+1.01e-6) exactly
        float wr = ST[(size_t)512 * MROWS + b * 64 + ni]
                 + ST[(size_t)513 * MROWS + b * 64 + nj];   // w rows unscaled
        float w  = __builtin_amdgcn_rcpf(1.f + __expf(-wr));
        float g  = -__logf(-__logf(gu[e]));
        en = __expf((w + g) * 2.0f);               // exp(logit), logit <= ~36: safe
        numer[e] = se * en;
    }
    // block reduce en for the softmax denominator: wave shuffle + 4-slot LDS
    #pragma unroll
    for (int o = 32; o; o >>= 1) en += __shfl_down(en, o);
    if ((tid & 63) == 0) sred[tid >> 6] = en;
    __syncthreads();
    if (tid == 0) atomicAdd((float*)&red[1], sred[0] + sred[1] + sred[2] + sred[3]);
}

// ---------------- final scatter (also zero-fills) ----------------
__global__ void k_out(const float* __restrict__ numer, const unsigned* __restrict__ red,
                      float* __restrict__ out) {
    int idx = blockIdx.x * 256 + threadIdx.x;
    if (idx >= Bg * Nn * Nn) return;
    int b = idx >> 12;
    int rem = idx & 4095;
    int r = rem >> 6, c = rem & 63;
    float v = 0.f;
    if (c > r) {
        int e = b * Ee + (r * (127 - r)) / 2 + (c - r - 1);
        float Sinv = __builtin_amdgcn_rcpf(((const float*)red)[1]);
        v = numer[e] * Sinv;
    }
    out[idx] = v;
}

extern "C" void kernel_launch(void* const* d_in, const int* in_sizes, int n_in,
                              void* d_out, int out_size, void* d_ws, size_t ws_size,
                              hipStream_t stream) {
    const float* topo = (const float*)d_in[0];
    const float* temp = (const float*)d_in[1];
    const float* gu   = (const float*)d_in[2];
    const float* Wg   = (const float*)d_in[3];
    const float* bg   = (const float*)d_in[4];
    const float* Wm   = (const float*)d_in[5];
    const float* bm   = (const float*)d_in[6];
    const float* Wv   = (const float*)d_in[7];
    const float* bv   = (const float*)d_in[8];
    const float* Ww   = (const float*)d_in[9];
    const float* bw   = (const float*)d_in[10];
    float* out = (float*)d_out;

    char* ws = (char*)d_ws;
    size_t off = 0;
    auto carve = [&](size_t bytes) { char* p = ws + off; off = (off + bytes + 255) & ~(size_t)255; return p; };

    // r1 hosts aggb (bf16, 5.2 MB) pre-GEMM1, then S_T[576][8192] f32 (18.9 MB).
    char*   r1    = carve((size_t)SCOLS * MROWS * 4);
    float*  ST    = (float*)r1;
    ushort* aggb  = (ushort*)r1;
    ushort* hb    = (ushort*)carve((size_t)MROWS * Hd * 2);      // 4.19 MB
    ushort* WgbT  = (ushort*)carve((size_t)INF * Hd * 2);        // 0.16 MB
    ushort* WcatT = (ushort*)carve((size_t)Hd * SCOLS * 2);      // 0.29 MB
    float*  ebias = (float*)carve((size_t)SCOLS * 4);
    float*  numer = (float*)carve((size_t)TOTE * 4);             // 1.03 MB
    unsigned* red = (unsigned*)carve(256);

    k_prep<<<(CVT_N + PACK_N + SCOLS + 255) / 256, 256, 0, stream>>>(
        Wg, Wm, Wv, Ww, bm, bv, bw, WgbT, WcatT, ebias, red);
    k_agg<<<dim3(Bg, INF / 64), 256, 0, stream>>>(topo, temp, aggb);
    // GEMM1: hb[8192,256] = relu(aggb[8192,320] @ WgbT^T + bg)
    k_gemm_mfma<<<dim3(Hd / 64, MROWS / 64), 256, 0, stream>>>(
        aggb, WgbT, bg, hb, nullptr, Hd, INF, 1, 0, 0);
    // GEMM2: ST[576][8192] = colxf((hb[8192,256] @ WcatT^T + ebias))^T
    k_gemm_mfma<<<dim3(SCOLS / 64, MROWS / 64), 256, 0, stream>>>(
        hb, WcatT, ebias, nullptr, ST, SCOLS, Hd, 0, 1, 1);
    k_edge4<<<Bg * 10, 256, 0, stream>>>(ST, gu, numer, red);
    k_out<<<(Bg * Nn * Nn + 255) / 256, 256, 0, stream>>>(numer, red, out);
}